// Round 5
// baseline (227.722 us; speedup 1.0000x reference)
//
#include <hip/hip_runtime.h>
#include <stdint.h>

#define SEQ 4096
#define DM 768
#define NH 12
#define HD 64

typedef __attribute__((ext_vector_type(8))) short bf8;
typedef __attribute__((ext_vector_type(4))) float f4;
typedef __attribute__((ext_vector_type(16))) float f32x16;

static __device__ __forceinline__ f4 mfma_bf16(bf8 a, bf8 b, f4 c) {
  return __builtin_amdgcn_mfma_f32_16x16x32_bf16(a, b, c, 0, 0, 0);
}
static __device__ __forceinline__ f32x16 mfma32(bf8 a, bf8 b, f32x16 c) {
  return __builtin_amdgcn_mfma_f32_32x32x16_bf16(a, b, c, 0, 0, 0);
}

// RNE float->bf16 (bit pattern)
static __device__ __forceinline__ unsigned short f2bf(float f) {
  unsigned int u = __float_as_uint(f);
  u += 0x7FFFu + ((u >> 16) & 1u);
  return (unsigned short)(u >> 16);
}

// packed f32 pair -> bf16 pair (lo in low 16, hi in high 16)
static __device__ __forceinline__ unsigned int cvtpk(float lo, float hi) {
  unsigned int r;
  asm("v_cvt_pk_bf16_f32 %0, %1, %2" : "=v"(r) : "v"(lo), "v"(hi));
  return r;
}

static __device__ __forceinline__ void gload_lds16(const void* g, void* l) {
  __builtin_amdgcn_global_load_lds(
      (const __attribute__((address_space(1))) void*)g,
      (__attribute__((address_space(3))) void*)l, 16, 0, 0);
}

// ---- cast x (fp32) -> bf16 -----------------------------------------------
__global__ __launch_bounds__(256) void k_cvt(const float* __restrict__ x,
                                             unsigned short* __restrict__ xb) {
  int i = (blockIdx.x * 256 + threadIdx.x) * 4;
  float4 v = *reinterpret_cast<const float4*>(x + i);
  ushort4 o;
  o.x = f2bf(v.x); o.y = f2bf(v.y); o.z = f2bf(v.z); o.w = f2bf(v.w);
  *reinterpret_cast<ushort4*>(xb + i) = o;
}

// ---- transpose+cast weights: WT[z][n][k] = bf16(W[k][n]) -----------------
__global__ __launch_bounds__(256) void k_tw(const float* __restrict__ w0,
                                            const float* __restrict__ w1,
                                            const float* __restrict__ w2,
                                            const float* __restrict__ w3,
                                            unsigned short* __restrict__ wt) {
  const float* W = blockIdx.z == 0 ? w0 : blockIdx.z == 1 ? w1
                 : blockIdx.z == 2 ? w2 : w3;
  unsigned short* WT = wt + (size_t)blockIdx.z * DM * DM;
  __shared__ float t[32][33];
  int c0 = blockIdx.x * 32, r0 = blockIdx.y * 32;
  int lx = threadIdx.x & 31, ly = threadIdx.x >> 5;
#pragma unroll
  for (int rr = 0; rr < 32; rr += 8)
    t[ly + rr][lx] = W[(size_t)(r0 + ly + rr) * DM + c0 + lx];
  __syncthreads();
#pragma unroll
  for (int rr = 0; rr < 32; rr += 8)
    WT[(size_t)(c0 + ly + rr) * DM + r0 + lx] = f2bf(t[lx][ly + rr]);
}

// ---- bf16 MFMA GEMM: C[4096][768] = A[4096][768] @ Bt[768][768]^T --------
// MODE 0: store bf16 [row][768] * scale   (Q gets softmax scale folded in)
// MODE 1: store bf16 transposed Vt[col][4096]
// MODE 2: store fp32 [row][768] + bias[col]
template <int MODE>
__global__ __launch_bounds__(256) void k_gemm(const unsigned short* __restrict__ A,
                                              const unsigned short* __restrict__ Bt,
                                              void* __restrict__ Cout,
                                              const float* __restrict__ bias,
                                              float scale) {
  constexpr int K = DM;
  __shared__ unsigned short sA[128 * 32];
  __shared__ unsigned short sB[64 * 32];
  const int t = threadIdx.x, lane = t & 63, w = t >> 6;
  const int wr = w >> 1, wc = w & 1;
  const int c = lane & 15, g = lane >> 4;
  const int brow = blockIdx.x * 128, bcol = blockIdx.y * 64;
  f4 acc[4][2] = {};
  for (int k0 = 0; k0 < K; k0 += 32) {
#pragma unroll
    for (int i = 0; i < 2; ++i) {
      int slot = w * 2 + i;
      int chunk = slot * 64 + lane;
      int row = chunk >> 2;
      int sl = (chunk & 3) ^ ((row >> 1) & 3);
      gload_lds16(A + (size_t)(brow + row) * K + k0 + sl * 8, &sA[slot * 512]);
    }
    {
      int chunk = w * 64 + lane;
      int row = chunk >> 2;
      int sl = (chunk & 3) ^ ((row >> 1) & 3);
      gload_lds16(Bt + (size_t)(bcol + row) * K + k0 + sl * 8, &sB[w * 512]);
    }
    __syncthreads();
    bf8 af[4], bfr[2];
#pragma unroll
    for (int m = 0; m < 4; ++m) {
      int row = wr * 64 + m * 16 + c;
      int off = row * 64 + ((g * 16) ^ (((row >> 1) & 3) << 4));
      af[m] = *reinterpret_cast<const bf8*>(reinterpret_cast<const char*>(sA) + off);
    }
#pragma unroll
    for (int n = 0; n < 2; ++n) {
      int row = wc * 32 + n * 16 + c;
      int off = row * 64 + ((g * 16) ^ (((row >> 1) & 3) << 4));
      bfr[n] = *reinterpret_cast<const bf8*>(reinterpret_cast<const char*>(sB) + off);
    }
#pragma unroll
    for (int m = 0; m < 4; ++m)
#pragma unroll
      for (int n = 0; n < 2; ++n)
        acc[m][n] = mfma_bf16(af[m], bfr[n], acc[m][n]);
    __syncthreads();
  }
#pragma unroll
  for (int m = 0; m < 4; ++m) {
#pragma unroll
    for (int n = 0; n < 2; ++n) {
      int col = bcol + wc * 32 + n * 16 + c;
      int row0 = brow + wr * 64 + m * 16 + g * 4;
      if (MODE == 0) {
        unsigned short* C = (unsigned short*)Cout;
#pragma unroll
        for (int r = 0; r < 4; ++r)
          C[(size_t)(row0 + r) * DM + col] = f2bf(acc[m][n][r] * scale);
      } else if (MODE == 1) {
        unsigned short* C = (unsigned short*)Cout;
        ushort4 p;
        p.x = f2bf(acc[m][n][0]); p.y = f2bf(acc[m][n][1]);
        p.z = f2bf(acc[m][n][2]); p.w = f2bf(acc[m][n][3]);
        *reinterpret_cast<ushort4*>(C + (size_t)col * SEQ + row0) = p;
      } else {
        float* C = (float*)Cout;
#pragma unroll
        for (int r = 0; r < 4; ++r)
          C[(size_t)(row0 + r) * DM + col] = acc[m][n][r] + bias[col];
      }
    }
  }
}

// ---- causal flash attention, split-K x4, XCD-chunked work mapping --------
// One 32-row q-tile per block. Work W = xcd*192 + slot keeps each XCD on
// ~1.5 heads (K+V ~1.5MB < 4MB L2); within an XCD, long q-tiles first.
// Each wave strides k-tiles by 4; K prefetched one tile ahead (register
// dbuf); 4-way LDS merge. Qb pre-scaled by log2(e)/sqrt(HD).
__global__ __launch_bounds__(256, 4) void k_attn(const unsigned short* __restrict__ Qb,
                                                 const unsigned short* __restrict__ Kb,
                                                 const unsigned short* __restrict__ Vt,
                                                 unsigned short* __restrict__ ctx) {
  const int tid = threadIdx.x;
  const int lane = tid & 63;
  const int w = tid >> 6;  // split-K wave index, 0..3
  const int ql = lane & 31, hi = lane >> 5;

  // XCD-chunked swizzle: dispatch-linear L -> (head, q-tile)
  const int L = (int)blockIdx.x + 128 * (int)blockIdx.y;  // 0..1535
  const int W = (L & 7) * 192 + (L >> 3);
  const int h = W >> 7;
  const int qt = 127 - (W & 127);  // long-first within each XCD chunk
  const size_t hd = (size_t)h * HD;

  __shared__ float sO[4][64][32];
  __shared__ float sM[4][32];
  __shared__ float sL[4][32];

  auto loadK = [&](bf8 (&kf)[4], int t) {
    const unsigned short* kp = Kb + (size_t)(t * 32 + ql) * DM + hd + hi * 8;
#pragma unroll
    for (int d = 0; d < 4; ++d)
      kf[d] = *reinterpret_cast<const bf8*>(kp + d * 16);
  };

  const int qg = qt * 32 + ql;
  // Q as B-fragments: col=q=lane&31, k(d)=8*hi+j
  bf8 qf[4];
  {
    const unsigned short* qp = Qb + (size_t)qg * DM + hd + hi * 8;
#pragma unroll
    for (int d = 0; d < 4; ++d)
      qf[d] = *reinterpret_cast<const bf8*>(qp + d * 16);
  }
  f32x16 o0 = {}, o1 = {};
  float m = -1e30f, l = 0.f;

  auto step = [&](bf8 (&kf)[4], int t) {
    const int k0 = t * 32;
    // V^T A-fragments: issue loads first (consumed after softmax)
    bf8 vf[2][2];
    {
      const unsigned short* vp = Vt + (hd + ql) * SEQ + k0 + hi * 8;
#pragma unroll
      for (int kh = 0; kh < 2; ++kh) {
        vf[kh][0] = *reinterpret_cast<const bf8*>(vp + kh * 16);
        vf[kh][1] = *reinterpret_cast<const bf8*>(vp + (size_t)32 * SEQ + kh * 16);
      }
    }
    // S^T[k][q] = K(32k x 16d) x Q(16d x 32q)
    f32x16 s = {};
    __builtin_amdgcn_s_setprio(1);
#pragma unroll
    for (int d = 0; d < 4; ++d)
      s = mfma32(kf[d], qf[d], s);
    __builtin_amdgcn_s_setprio(0);
    if (t == qt) {  // diagonal tile: causal mask
#pragma unroll
      for (int r = 0; r < 16; ++r) {
        int kr = k0 + (r & 3) + 8 * (r >> 2) + 4 * hi;
        s[r] = (kr > qg) ? -1e30f : s[r];
      }
    }
    // online softmax (scores already in log2 scale)
    float tm = s[0];
#pragma unroll
    for (int r = 1; r < 16; ++r) tm = fmaxf(tm, s[r]);
    tm = fmaxf(tm, __shfl_xor(tm, 32));
    float mn = fmaxf(m, tm);
    float al = __builtin_amdgcn_exp2f(m - mn);
    m = mn;
    float p[16];
    float ls = 0.f;
#pragma unroll
    for (int r = 0; r < 16; ++r) {
      p[r] = __builtin_amdgcn_exp2f(s[r] - mn);
      ls += p[r];
    }
    ls += __shfl_xor(ls, 32);
    l = l * al + ls;
#pragma unroll
    for (int r = 0; r < 16; ++r) { o0[r] *= al; o1[r] *= al; }
    // P^T -> B-fragments via cvt_pk + permlane32_swap.
    bf8 pf[2];
#pragma unroll
    for (int kh = 0; kh < 2; ++kh) {
      unsigned int A0 = cvtpk(p[kh * 8 + 0], p[kh * 8 + 1]);
      unsigned int A1 = cvtpk(p[kh * 8 + 2], p[kh * 8 + 3]);
      unsigned int B0 = cvtpk(p[kh * 8 + 4], p[kh * 8 + 5]);
      unsigned int B1 = cvtpk(p[kh * 8 + 6], p[kh * 8 + 7]);
      asm volatile("v_permlane32_swap_b32 %0, %1" : "+v"(A0), "+v"(B0));
      asm volatile("v_permlane32_swap_b32 %0, %1" : "+v"(A1), "+v"(B1));
      uint4 wds = {A0, A1, B0, B1};
      pf[kh] = *reinterpret_cast<bf8*>(&wds);
    }
    // O^T[d][q] += V^T(32d x 16k) x P^T(16k x 32q)
    __builtin_amdgcn_s_setprio(1);
#pragma unroll
    for (int kh = 0; kh < 2; ++kh) {
      o0 = mfma32(vf[kh][0], pf[kh], o0);
      o1 = mfma32(vf[kh][1], pf[kh], o1);
    }
    __builtin_amdgcn_s_setprio(0);
  };

  // pipelined loop over this wave's tiles: t = w + 4*i
  const int nt = (qt >= w) ? ((qt - w) >> 2) + 1 : 0;
  bf8 kA[4], kB[4];
  if (nt > 0) loadK(kA, w);
  int i = 0;
  for (; i + 2 <= nt; i += 2) {
    loadK(kB, w + (i + 1) * 4);
    step(kA, w + i * 4);
    if (i + 2 < nt) loadK(kA, w + (i + 2) * 4);
    step(kB, w + (i + 1) * 4);
  }
  if (i < nt) step(kA, w + i * 4);

  // ---- 4-way split-K merge via LDS ----
#pragma unroll
  for (int r = 0; r < 16; ++r) {
    int dr = (r & 3) + 8 * (r >> 2) + 4 * hi;
    sO[w][dr][ql] = o0[r];
    sO[w][32 + dr][ql] = o1[r];
  }
  if (hi == 0) { sM[w][ql] = m; sL[w][ql] = l; }
  __syncthreads();
  {
    const int q = tid & 31;
    const int dblk = tid >> 5;  // 0..7, 8 d-values each
    float m0 = sM[0][q], m1 = sM[1][q], m2 = sM[2][q], m3 = sM[3][q];
    float mn = fmaxf(fmaxf(m0, m1), fmaxf(m2, m3));
    float a0 = __builtin_amdgcn_exp2f(m0 - mn);
    float a1 = __builtin_amdgcn_exp2f(m1 - mn);
    float a2 = __builtin_amdgcn_exp2f(m2 - mn);
    float a3 = __builtin_amdgcn_exp2f(m3 - mn);
    float inv = 1.f / (a0 * sL[0][q] + a1 * sL[1][q] + a2 * sL[2][q] + a3 * sL[3][q]);
    a0 *= inv; a1 *= inv; a2 *= inv; a3 *= inv;
    unsigned short* cp = ctx + (size_t)(qt * 32 + q) * DM + hd + dblk * 8;
#pragma unroll
    for (int j = 0; j < 8; j += 2) {
      int d = dblk * 8 + j;
      float v0 = sO[0][d][q] * a0 + sO[1][d][q] * a1 + sO[2][d][q] * a2 + sO[3][d][q] * a3;
      float v1 = sO[0][d + 1][q] * a0 + sO[1][d + 1][q] * a1 + sO[2][d + 1][q] * a2 + sO[3][d + 1][q] * a3;
      *reinterpret_cast<unsigned int*>(cp + j) = cvtpk(v0, v1);
    }
  }
}

extern "C" void kernel_launch(void* const* d_in, const int* in_sizes, int n_in,
                              void* d_out, int out_size, void* d_ws, size_t ws_size,
                              hipStream_t stream) {
  const float* x  = (const float*)d_in[0];
  const float* Wq = (const float*)d_in[1];
  const float* Wk = (const float*)d_in[2];
  const float* Wv = (const float*)d_in[3];
  const float* Wo = (const float*)d_in[4];
  const float* bo = (const float*)d_in[5];

  unsigned short* xb = (unsigned short*)d_ws;
  unsigned short* wt = xb + (size_t)SEQ * DM;
  unsigned short* Qb = wt + (size_t)4 * DM * DM;
  unsigned short* Kb = Qb + (size_t)SEQ * DM;
  unsigned short* Vt = Kb + (size_t)SEQ * DM;
  unsigned short* cx = Vt + (size_t)SEQ * DM;

  const float qscale = 1.4426950408889634f / 8.0f;  // log2(e)/sqrt(HD)

  k_cvt<<<(SEQ * DM) / 1024, 256, 0, stream>>>(x, xb);
  k_tw<<<dim3(24, 24, 4), 256, 0, stream>>>(Wq, Wk, Wv, Wo, wt);
  dim3 gg(SEQ / 128, DM / 64);
  k_gemm<0><<<gg, 256, 0, stream>>>(xb, wt, Qb, nullptr, qscale);
  k_gemm<0><<<gg, 256, 0, stream>>>(xb, wt + (size_t)DM * DM, Kb, nullptr, 1.0f);
  k_gemm<1><<<gg, 256, 0, stream>>>(xb, wt + (size_t)2 * DM * DM, Vt, nullptr, 1.0f);
  k_attn<<<dim3(128, NH), 256, 0, stream>>>(Qb, Kb, Vt, cx);
  k_gemm<2><<<gg, 256, 0, stream>>>(cx, wt + (size_t)3 * DM * DM, d_out, bo, 1.0f);
}

// Round 6
// 161.661 us; speedup vs baseline: 1.4086x; 1.4086x over previous
//
#include <hip/hip_runtime.h>
#include <stdint.h>

#define SEQ 4096
#define DM 768
#define NH 12
#define HD 64

typedef __attribute__((ext_vector_type(8))) short bf8;
typedef __attribute__((ext_vector_type(4))) float f4;
typedef __attribute__((ext_vector_type(16))) float f32x16;

static __device__ __forceinline__ f4 mfma_bf16(bf8 a, bf8 b, f4 c) {
  return __builtin_amdgcn_mfma_f32_16x16x32_bf16(a, b, c, 0, 0, 0);
}
static __device__ __forceinline__ f32x16 mfma32(bf8 a, bf8 b, f32x16 c) {
  return __builtin_amdgcn_mfma_f32_32x32x16_bf16(a, b, c, 0, 0, 0);
}

// RNE float->bf16 (bit pattern)
static __device__ __forceinline__ unsigned short f2bf(float f) {
  unsigned int u = __float_as_uint(f);
  u += 0x7FFFu + ((u >> 16) & 1u);
  return (unsigned short)(u >> 16);
}

// packed f32 pair -> bf16 pair (lo in low 16, hi in high 16)
static __device__ __forceinline__ unsigned int cvtpk(float lo, float hi) {
  unsigned int r;
  asm("v_cvt_pk_bf16_f32 %0, %1, %2" : "=v"(r) : "v"(lo), "v"(hi));
  return r;
}

static __device__ __forceinline__ void gload_lds16(const void* g, void* l) {
  __builtin_amdgcn_global_load_lds(
      (const __attribute__((address_space(1))) void*)g,
      (__attribute__((address_space(3))) void*)l, 16, 0, 0);
}

// ---- cast x (fp32) -> bf16 -----------------------------------------------
__global__ __launch_bounds__(256) void k_cvt(const float* __restrict__ x,
                                             unsigned short* __restrict__ xb) {
  int i = (blockIdx.x * 256 + threadIdx.x) * 4;
  float4 v = *reinterpret_cast<const float4*>(x + i);
  ushort4 o;
  o.x = f2bf(v.x); o.y = f2bf(v.y); o.z = f2bf(v.z); o.w = f2bf(v.w);
  *reinterpret_cast<ushort4*>(xb + i) = o;
}

// ---- transpose+cast weights: WT[z][n][k] = bf16(W[k][n]) -----------------
__global__ __launch_bounds__(256) void k_tw(const float* __restrict__ w0,
                                            const float* __restrict__ w1,
                                            const float* __restrict__ w2,
                                            const float* __restrict__ w3,
                                            unsigned short* __restrict__ wt) {
  const float* W = blockIdx.z == 0 ? w0 : blockIdx.z == 1 ? w1
                 : blockIdx.z == 2 ? w2 : w3;
  unsigned short* WT = wt + (size_t)blockIdx.z * DM * DM;
  __shared__ float t[32][33];
  int c0 = blockIdx.x * 32, r0 = blockIdx.y * 32;
  int lx = threadIdx.x & 31, ly = threadIdx.x >> 5;
#pragma unroll
  for (int rr = 0; rr < 32; rr += 8)
    t[ly + rr][lx] = W[(size_t)(r0 + ly + rr) * DM + c0 + lx];
  __syncthreads();
#pragma unroll
  for (int rr = 0; rr < 32; rr += 8)
    WT[(size_t)(c0 + ly + rr) * DM + r0 + lx] = f2bf(t[lx][ly + rr]);
}

// ---- bf16 MFMA GEMM: C[4096][768] = A[4096][768] @ Bt[768][768]^T --------
// MODE 0: store bf16 [row][768] * scale   (Q gets softmax scale folded in)
// MODE 1: store bf16 transposed Vt[col][4096]
// MODE 2: store fp32 [row][768] + bias[col]
template <int MODE>
__global__ __launch_bounds__(256) void k_gemm(const unsigned short* __restrict__ A,
                                              const unsigned short* __restrict__ Bt,
                                              void* __restrict__ Cout,
                                              const float* __restrict__ bias,
                                              float scale) {
  constexpr int K = DM;
  __shared__ unsigned short sA[128 * 32];
  __shared__ unsigned short sB[64 * 32];
  const int t = threadIdx.x, lane = t & 63, w = t >> 6;
  const int wr = w >> 1, wc = w & 1;
  const int c = lane & 15, g = lane >> 4;
  const int brow = blockIdx.x * 128, bcol = blockIdx.y * 64;
  f4 acc[4][2] = {};
  for (int k0 = 0; k0 < K; k0 += 32) {
#pragma unroll
    for (int i = 0; i < 2; ++i) {
      int slot = w * 2 + i;
      int chunk = slot * 64 + lane;
      int row = chunk >> 2;
      int sl = (chunk & 3) ^ ((row >> 1) & 3);
      gload_lds16(A + (size_t)(brow + row) * K + k0 + sl * 8, &sA[slot * 512]);
    }
    {
      int chunk = w * 64 + lane;
      int row = chunk >> 2;
      int sl = (chunk & 3) ^ ((row >> 1) & 3);
      gload_lds16(Bt + (size_t)(bcol + row) * K + k0 + sl * 8, &sB[w * 512]);
    }
    __syncthreads();
    bf8 af[4], bfr[2];
#pragma unroll
    for (int m = 0; m < 4; ++m) {
      int row = wr * 64 + m * 16 + c;
      int off = row * 64 + ((g * 16) ^ (((row >> 1) & 3) << 4));
      af[m] = *reinterpret_cast<const bf8*>(reinterpret_cast<const char*>(sA) + off);
    }
#pragma unroll
    for (int n = 0; n < 2; ++n) {
      int row = wc * 32 + n * 16 + c;
      int off = row * 64 + ((g * 16) ^ (((row >> 1) & 3) << 4));
      bfr[n] = *reinterpret_cast<const bf8*>(reinterpret_cast<const char*>(sB) + off);
    }
#pragma unroll
    for (int m = 0; m < 4; ++m)
#pragma unroll
      for (int n = 0; n < 2; ++n)
        acc[m][n] = mfma_bf16(af[m], bfr[n], acc[m][n]);
    __syncthreads();
  }
#pragma unroll
  for (int m = 0; m < 4; ++m) {
#pragma unroll
    for (int n = 0; n < 2; ++n) {
      int col = bcol + wc * 32 + n * 16 + c;
      int row0 = brow + wr * 64 + m * 16 + g * 4;
      if (MODE == 0) {
        unsigned short* C = (unsigned short*)Cout;
#pragma unroll
        for (int r = 0; r < 4; ++r)
          C[(size_t)(row0 + r) * DM + col] = f2bf(acc[m][n][r] * scale);
      } else if (MODE == 1) {
        unsigned short* C = (unsigned short*)Cout;
        ushort4 p;
        p.x = f2bf(acc[m][n][0]); p.y = f2bf(acc[m][n][1]);
        p.z = f2bf(acc[m][n][2]); p.w = f2bf(acc[m][n][3]);
        *reinterpret_cast<ushort4*>(C + (size_t)col * SEQ + row0) = p;
      } else {
        float* C = (float*)Cout;
#pragma unroll
        for (int r = 0; r < 4; ++r)
          C[(size_t)(row0 + r) * DM + col] = acc[m][n][r] + bias[col];
      }
    }
  }
}

// ---- causal flash attention: paired q-tiles + split-K x4 + XCD chunking --
// Block = 4 waves, handles q-tiles {b, 127-b} -> uniform 129 tiles/block,
// 768 blocks = exactly 3/CU (perfect balance). 1D grid; W=(L&7)*96+(L>>3)
// gives each XCD 96 consecutive paired-blocks = 1.5 heads (K+V ~1.5MB,
// L2-resident). Each wave strides k-tiles by 4; K prefetched one tile
// ahead (register dbuf); 4-way LDS merge. Qb pre-scaled by log2(e)/sqrt(HD).
__global__ __launch_bounds__(256, 3) void k_attn(const unsigned short* __restrict__ Qb,
                                                 const unsigned short* __restrict__ Kb,
                                                 const unsigned short* __restrict__ Vt,
                                                 unsigned short* __restrict__ ctx) {
  const int tid = threadIdx.x;
  const int lane = tid & 63;
  const int w = tid >> 6;  // split-K wave index, 0..3
  const int ql = lane & 31, hi = lane >> 5;

  // XCD-chunked swizzle: each XCD (L&7) owns 96 consecutive works
  const int L = (int)blockIdx.x;          // 0..767
  const int W = (L & 7) * 96 + (L >> 3);  // chunked work id
  const int h = W >> 6;
  const int b = W & 63;
  const size_t hd = (size_t)h * HD;

  __shared__ float sO[4][64][32];
  __shared__ float sM[4][32];
  __shared__ float sL[4][32];

  auto loadK = [&](bf8 (&kf)[4], int t) {
    const unsigned short* kp = Kb + (size_t)(t * 32 + ql) * DM + hd + hi * 8;
#pragma unroll
    for (int d = 0; d < 4; ++d)
      kf[d] = *reinterpret_cast<const bf8*>(kp + d * 16);
  };

  auto phase = [&](int qt) {
    const int qg = qt * 32 + ql;
    // Q as B-fragments: col=q=lane&31, k(d)=8*hi+j
    bf8 qf[4];
    {
      const unsigned short* qp = Qb + (size_t)qg * DM + hd + hi * 8;
#pragma unroll
      for (int d = 0; d < 4; ++d)
        qf[d] = *reinterpret_cast<const bf8*>(qp + d * 16);
    }
    f32x16 o0 = {}, o1 = {};
    float m = -1e30f, l = 0.f;

    auto step = [&](bf8 (&kf)[4], int t) {
      const int k0 = t * 32;
      // V^T A-fragments: issue loads first (consumed after softmax)
      bf8 vf[2][2];
      {
        const unsigned short* vp = Vt + (hd + ql) * SEQ + k0 + hi * 8;
#pragma unroll
        for (int kh = 0; kh < 2; ++kh) {
          vf[kh][0] = *reinterpret_cast<const bf8*>(vp + kh * 16);
          vf[kh][1] = *reinterpret_cast<const bf8*>(vp + (size_t)32 * SEQ + kh * 16);
        }
      }
      // S^T[k][q] = K(32k x 16d) x Q(16d x 32q)
      f32x16 s = {};
      __builtin_amdgcn_s_setprio(1);
#pragma unroll
      for (int d = 0; d < 4; ++d)
        s = mfma32(kf[d], qf[d], s);
      __builtin_amdgcn_s_setprio(0);
      if (t == qt) {  // diagonal tile: causal mask
#pragma unroll
        for (int r = 0; r < 16; ++r) {
          int kr = k0 + (r & 3) + 8 * (r >> 2) + 4 * hi;
          s[r] = (kr > qg) ? -1e30f : s[r];
        }
      }
      // online softmax (scores already in log2 scale)
      float tm = s[0];
#pragma unroll
      for (int r = 1; r < 16; ++r) tm = fmaxf(tm, s[r]);
      tm = fmaxf(tm, __shfl_xor(tm, 32));
      float mn = fmaxf(m, tm);
      float al = __builtin_amdgcn_exp2f(m - mn);
      m = mn;
      float p[16];
      float ls = 0.f;
#pragma unroll
      for (int r = 0; r < 16; ++r) {
        p[r] = __builtin_amdgcn_exp2f(s[r] - mn);
        ls += p[r];
      }
      ls += __shfl_xor(ls, 32);
      l = l * al + ls;
#pragma unroll
      for (int r = 0; r < 16; ++r) { o0[r] *= al; o1[r] *= al; }
      // P^T -> B-fragments via cvt_pk + permlane32_swap.
      bf8 pf[2];
#pragma unroll
      for (int kh = 0; kh < 2; ++kh) {
        unsigned int A0 = cvtpk(p[kh * 8 + 0], p[kh * 8 + 1]);
        unsigned int A1 = cvtpk(p[kh * 8 + 2], p[kh * 8 + 3]);
        unsigned int B0 = cvtpk(p[kh * 8 + 4], p[kh * 8 + 5]);
        unsigned int B1 = cvtpk(p[kh * 8 + 6], p[kh * 8 + 7]);
        asm volatile("v_permlane32_swap_b32 %0, %1" : "+v"(A0), "+v"(B0));
        asm volatile("v_permlane32_swap_b32 %0, %1" : "+v"(A1), "+v"(B1));
        uint4 wds = {A0, A1, B0, B1};
        pf[kh] = *reinterpret_cast<bf8*>(&wds);
      }
      // O^T[d][q] += V^T(32d x 16k) x P^T(16k x 32q)
      __builtin_amdgcn_s_setprio(1);
#pragma unroll
      for (int kh = 0; kh < 2; ++kh) {
        o0 = mfma32(vf[kh][0], pf[kh], o0);
        o1 = mfma32(vf[kh][1], pf[kh], o1);
      }
      __builtin_amdgcn_s_setprio(0);
    };

    // pipelined loop over this wave's tiles: t = w + 4*i
    const int nt = (qt >= w) ? ((qt - w) >> 2) + 1 : 0;
    bf8 kA[4], kB[4];
    if (nt > 0) loadK(kA, w);
    int i = 0;
    for (; i + 2 <= nt; i += 2) {
      loadK(kB, w + (i + 1) * 4);
      step(kA, w + i * 4);
      if (i + 2 < nt) loadK(kA, w + (i + 2) * 4);
      step(kB, w + (i + 1) * 4);
    }
    if (i < nt) step(kA, w + i * 4);

    // ---- 4-way split-K merge via LDS ----
#pragma unroll
    for (int r = 0; r < 16; ++r) {
      int dr = (r & 3) + 8 * (r >> 2) + 4 * hi;
      sO[w][dr][ql] = o0[r];
      sO[w][32 + dr][ql] = o1[r];
    }
    if (hi == 0) { sM[w][ql] = m; sL[w][ql] = l; }
    __syncthreads();
    {
      const int q = tid & 31;
      const int dblk = tid >> 5;  // 0..7, 8 d-values each
      float m0 = sM[0][q], m1 = sM[1][q], m2 = sM[2][q], m3 = sM[3][q];
      float mn = fmaxf(fmaxf(m0, m1), fmaxf(m2, m3));
      float a0 = __builtin_amdgcn_exp2f(m0 - mn);
      float a1 = __builtin_amdgcn_exp2f(m1 - mn);
      float a2 = __builtin_amdgcn_exp2f(m2 - mn);
      float a3 = __builtin_amdgcn_exp2f(m3 - mn);
      float inv = 1.f / (a0 * sL[0][q] + a1 * sL[1][q] + a2 * sL[2][q] + a3 * sL[3][q]);
      a0 *= inv; a1 *= inv; a2 *= inv; a3 *= inv;
      unsigned short* cp = ctx + (size_t)(qt * 32 + q) * DM + hd + dblk * 8;
#pragma unroll
      for (int j = 0; j < 8; j += 2) {
        int d = dblk * 8 + j;
        float v0 = sO[0][d][q] * a0 + sO[1][d][q] * a1 + sO[2][d][q] * a2 + sO[3][d][q] * a3;
        float v1 = sO[0][d + 1][q] * a0 + sO[1][d + 1][q] * a1 + sO[2][d + 1][q] * a2 + sO[3][d + 1][q] * a3;
        *reinterpret_cast<unsigned int*>(cp + j) = cvtpk(v0, v1);
      }
    }
    __syncthreads();
  };

  phase(b);
  phase(127 - b);
}

extern "C" void kernel_launch(void* const* d_in, const int* in_sizes, int n_in,
                              void* d_out, int out_size, void* d_ws, size_t ws_size,
                              hipStream_t stream) {
  const float* x  = (const float*)d_in[0];
  const float* Wq = (const float*)d_in[1];
  const float* Wk = (const float*)d_in[2];
  const float* Wv = (const float*)d_in[3];
  const float* Wo = (const float*)d_in[4];
  const float* bo = (const float*)d_in[5];

  unsigned short* xb = (unsigned short*)d_ws;
  unsigned short* wt = xb + (size_t)SEQ * DM;
  unsigned short* Qb = wt + (size_t)4 * DM * DM;
  unsigned short* Kb = Qb + (size_t)SEQ * DM;
  unsigned short* Vt = Kb + (size_t)SEQ * DM;
  unsigned short* cx = Vt + (size_t)SEQ * DM;

  const float qscale = 1.4426950408889634f / 8.0f;  // log2(e)/sqrt(HD)

  k_cvt<<<(SEQ * DM) / 1024, 256, 0, stream>>>(x, xb);
  k_tw<<<dim3(24, 24, 4), 256, 0, stream>>>(Wq, Wk, Wv, Wo, wt);
  dim3 gg(SEQ / 128, DM / 64);
  k_gemm<0><<<gg, 256, 0, stream>>>(xb, wt, Qb, nullptr, qscale);
  k_gemm<0><<<gg, 256, 0, stream>>>(xb, wt + (size_t)DM * DM, Kb, nullptr, 1.0f);
  k_gemm<1><<<gg, 256, 0, stream>>>(xb, wt + (size_t)2 * DM * DM, Vt, nullptr, 1.0f);
  k_attn<<<dim3(768), 256, 0, stream>>>(Qb, Kb, Vt, cx);
  k_gemm<2><<<gg, 256, 0, stream>>>(cx, wt + (size_t)3 * DM * DM, d_out, bo, 1.0f);
}

// Round 8
// 161.530 us; speedup vs baseline: 1.4098x; 1.0008x over previous
//
#include <hip/hip_runtime.h>
#include <stdint.h>

#define SEQ 4096
#define DM 768
#define NH 12
#define HD 64

typedef __attribute__((ext_vector_type(8))) short bf8;
typedef __attribute__((ext_vector_type(4))) float f4;
typedef __attribute__((ext_vector_type(16))) float f32x16;

static __device__ __forceinline__ f4 mfma_bf16(bf8 a, bf8 b, f4 c) {
  return __builtin_amdgcn_mfma_f32_16x16x32_bf16(a, b, c, 0, 0, 0);
}
static __device__ __forceinline__ f32x16 mfma32(bf8 a, bf8 b, f32x16 c) {
  return __builtin_amdgcn_mfma_f32_32x32x16_bf16(a, b, c, 0, 0, 0);
}

// RNE float->bf16 (bit pattern)
static __device__ __forceinline__ unsigned short f2bf(float f) {
  unsigned int u = __float_as_uint(f);
  u += 0x7FFFu + ((u >> 16) & 1u);
  return (unsigned short)(u >> 16);
}

// packed f32 pair -> bf16 pair (lo in low 16, hi in high 16)
static __device__ __forceinline__ unsigned int cvtpk(float lo, float hi) {
  unsigned int r;
  asm("v_cvt_pk_bf16_f32 %0, %1, %2" : "=v"(r) : "v"(lo), "v"(hi));
  return r;
}

static __device__ __forceinline__ void gload_lds16(const void* g, void* l) {
  __builtin_amdgcn_global_load_lds(
      (const __attribute__((address_space(1))) void*)g,
      (__attribute__((address_space(3))) void*)l, 16, 0, 0);
}

// ---- cast x (fp32) -> bf16 -----------------------------------------------
__global__ __launch_bounds__(256) void k_cvt(const float* __restrict__ x,
                                             unsigned short* __restrict__ xb) {
  int i = (blockIdx.x * 256 + threadIdx.x) * 4;
  float4 v = *reinterpret_cast<const float4*>(x + i);
  ushort4 o;
  o.x = f2bf(v.x); o.y = f2bf(v.y); o.z = f2bf(v.z); o.w = f2bf(v.w);
  *reinterpret_cast<ushort4*>(xb + i) = o;
}

// ---- transpose+cast weights: WT[z][n][k] = bf16(W[k][n]) -----------------
__global__ __launch_bounds__(256) void k_tw(const float* __restrict__ w0,
                                            const float* __restrict__ w1,
                                            const float* __restrict__ w2,
                                            const float* __restrict__ w3,
                                            unsigned short* __restrict__ wt) {
  const float* W = blockIdx.z == 0 ? w0 : blockIdx.z == 1 ? w1
                 : blockIdx.z == 2 ? w2 : w3;
  unsigned short* WT = wt + (size_t)blockIdx.z * DM * DM;
  __shared__ float t[32][33];
  int c0 = blockIdx.x * 32, r0 = blockIdx.y * 32;
  int lx = threadIdx.x & 31, ly = threadIdx.x >> 5;
#pragma unroll
  for (int rr = 0; rr < 32; rr += 8)
    t[ly + rr][lx] = W[(size_t)(r0 + ly + rr) * DM + c0 + lx];
  __syncthreads();
#pragma unroll
  for (int rr = 0; rr < 32; rr += 8)
    WT[(size_t)(c0 + ly + rr) * DM + r0 + lx] = f2bf(t[lx][ly + rr]);
}

// ---- bf16 MFMA GEMM: C[4096][768] = A[4096][768] @ Bt[768][768]^T --------
// MODE 0: store bf16 [row][768] * scale   (Q gets softmax scale folded in)
// MODE 1: store bf16 transposed Vt[col][4096]
// MODE 2: store fp32 [row][768] + bias[col]
template <int MODE>
__global__ __launch_bounds__(256) void k_gemm(const unsigned short* __restrict__ A,
                                              const unsigned short* __restrict__ Bt,
                                              void* __restrict__ Cout,
                                              const float* __restrict__ bias,
                                              float scale) {
  constexpr int K = DM;
  __shared__ unsigned short sA[128 * 32];
  __shared__ unsigned short sB[64 * 32];
  const int t = threadIdx.x, lane = t & 63, w = t >> 6;
  const int wr = w >> 1, wc = w & 1;
  const int c = lane & 15, g = lane >> 4;
  const int brow = blockIdx.x * 128, bcol = blockIdx.y * 64;
  f4 acc[4][2] = {};
  for (int k0 = 0; k0 < K; k0 += 32) {
#pragma unroll
    for (int i = 0; i < 2; ++i) {
      int slot = w * 2 + i;
      int chunk = slot * 64 + lane;
      int row = chunk >> 2;
      int sl = (chunk & 3) ^ ((row >> 1) & 3);
      gload_lds16(A + (size_t)(brow + row) * K + k0 + sl * 8, &sA[slot * 512]);
    }
    {
      int chunk = w * 64 + lane;
      int row = chunk >> 2;
      int sl = (chunk & 3) ^ ((row >> 1) & 3);
      gload_lds16(Bt + (size_t)(bcol + row) * K + k0 + sl * 8, &sB[w * 512]);
    }
    __syncthreads();
    bf8 af[4], bfr[2];
#pragma unroll
    for (int m = 0; m < 4; ++m) {
      int row = wr * 64 + m * 16 + c;
      int off = row * 64 + ((g * 16) ^ (((row >> 1) & 3) << 4));
      af[m] = *reinterpret_cast<const bf8*>(reinterpret_cast<const char*>(sA) + off);
    }
#pragma unroll
    for (int n = 0; n < 2; ++n) {
      int row = wc * 32 + n * 16 + c;
      int off = row * 64 + ((g * 16) ^ (((row >> 1) & 3) << 4));
      bfr[n] = *reinterpret_cast<const bf8*>(reinterpret_cast<const char*>(sB) + off);
    }
#pragma unroll
    for (int m = 0; m < 4; ++m)
#pragma unroll
      for (int n = 0; n < 2; ++n)
        acc[m][n] = mfma_bf16(af[m], bfr[n], acc[m][n]);
    __syncthreads();
  }
#pragma unroll
  for (int m = 0; m < 4; ++m) {
#pragma unroll
    for (int n = 0; n < 2; ++n) {
      int col = bcol + wc * 32 + n * 16 + c;
      int row0 = brow + wr * 64 + m * 16 + g * 4;
      if (MODE == 0) {
        unsigned short* C = (unsigned short*)Cout;
#pragma unroll
        for (int r = 0; r < 4; ++r)
          C[(size_t)(row0 + r) * DM + col] = f2bf(acc[m][n][r] * scale);
      } else if (MODE == 1) {
        unsigned short* C = (unsigned short*)Cout;
        ushort4 p;
        p.x = f2bf(acc[m][n][0]); p.y = f2bf(acc[m][n][1]);
        p.z = f2bf(acc[m][n][2]); p.w = f2bf(acc[m][n][3]);
        *reinterpret_cast<ushort4*>(C + (size_t)col * SEQ + row0) = p;
      } else {
        float* C = (float*)Cout;
#pragma unroll
        for (int r = 0; r < 4; ++r)
          C[(size_t)(row0 + r) * DM + col] = acc[m][n][r] + bias[col];
      }
    }
  }
}

// ---- attention helpers (straight-line macros; names from enclosing scope) --
#define LOADK(kf, t) do {                                                     \
    const unsigned short* kp_ = Kbase + (size_t)(t) * (32 * DM);              \
    kf[0] = *reinterpret_cast<const bf8*>(kp_);                               \
    kf[1] = *reinterpret_cast<const bf8*>(kp_ + 16);                          \
    kf[2] = *reinterpret_cast<const bf8*>(kp_ + 32);                          \
    kf[3] = *reinterpret_cast<const bf8*>(kp_ + 48);                          \
  } while (0)

#define LOADV(vf, t) do {                                                     \
    const unsigned short* vp_ = Vbase + (t) * 32;                             \
    vf[0] = *reinterpret_cast<const bf8*>(vp_);                               \
    vf[1] = *reinterpret_cast<const bf8*>(vp_ + 16);                          \
    vf[2] = *reinterpret_cast<const bf8*>(vp_ + (size_t)32 * SEQ);            \
    vf[3] = *reinterpret_cast<const bf8*>(vp_ + (size_t)32 * SEQ + 16);       \
  } while (0)

#define PSWAP(a, b) asm volatile("v_permlane32_swap_b32 %0, %1" : "+v"(a), "+v"(b))

#define STEP(kf, vf, t) do {                                                  \
    f32x16 s_ = {};                                                           \
    __builtin_amdgcn_s_setprio(1);                                            \
    s_ = mfma32(kf[0], qf[0], s_);                                            \
    s_ = mfma32(kf[1], qf[1], s_);                                            \
    s_ = mfma32(kf[2], qf[2], s_);                                            \
    s_ = mfma32(kf[3], qf[3], s_);                                            \
    __builtin_amdgcn_s_setprio(0);                                            \
    if ((t) == qt) {                                                          \
      _Pragma("unroll")                                                       \
      for (int r_ = 0; r_ < 16; ++r_) {                                       \
        int kr_ = (t) * 32 + (r_ & 3) + 8 * (r_ >> 2) + 4 * hi;               \
        s_[r_] = (kr_ > qg) ? -1e30f : s_[r_];                                \
      }                                                                       \
    }                                                                         \
    float tm_ = fmaxf(fmaxf(fmaxf(fmaxf(s_[0], s_[1]), fmaxf(s_[2], s_[3])), \
                            fmaxf(fmaxf(s_[4], s_[5]), fmaxf(s_[6], s_[7]))),\
                      fmaxf(fmaxf(fmaxf(s_[8], s_[9]), fmaxf(s_[10], s_[11])),\
                            fmaxf(fmaxf(s_[12], s_[13]), fmaxf(s_[14], s_[15]))));\
    tm_ = fmaxf(tm_, __shfl_xor(tm_, 32));                                    \
    float mn_ = fmaxf(m, tm_);                                                \
    float al_ = __builtin_amdgcn_exp2f(m - mn_);                              \
    m = mn_;                                                                  \
    float p0_ = __builtin_amdgcn_exp2f(s_[0] - mn_);                          \
    float p1_ = __builtin_amdgcn_exp2f(s_[1] - mn_);                          \
    float p2_ = __builtin_amdgcn_exp2f(s_[2] - mn_);                          \
    float p3_ = __builtin_amdgcn_exp2f(s_[3] - mn_);                          \
    float p4_ = __builtin_amdgcn_exp2f(s_[4] - mn_);                          \
    float p5_ = __builtin_amdgcn_exp2f(s_[5] - mn_);                          \
    float p6_ = __builtin_amdgcn_exp2f(s_[6] - mn_);                          \
    float p7_ = __builtin_amdgcn_exp2f(s_[7] - mn_);                          \
    unsigned int wa0_ = cvtpk(p0_, p1_), wa1_ = cvtpk(p2_, p3_);              \
    unsigned int wb0_ = cvtpk(p4_, p5_), wb1_ = cvtpk(p6_, p7_);              \
    float ls_ = ((p0_ + p1_) + (p2_ + p3_)) + ((p4_ + p5_) + (p6_ + p7_));    \
    float q0_ = __builtin_amdgcn_exp2f(s_[8] - mn_);                          \
    float q1_ = __builtin_amdgcn_exp2f(s_[9] - mn_);                          \
    float q2_ = __builtin_amdgcn_exp2f(s_[10] - mn_);                         \
    float q3_ = __builtin_amdgcn_exp2f(s_[11] - mn_);                         \
    float q4_ = __builtin_amdgcn_exp2f(s_[12] - mn_);                         \
    float q5_ = __builtin_amdgcn_exp2f(s_[13] - mn_);                         \
    float q6_ = __builtin_amdgcn_exp2f(s_[14] - mn_);                         \
    float q7_ = __builtin_amdgcn_exp2f(s_[15] - mn_);                         \
    unsigned int wc0_ = cvtpk(q0_, q1_), wc1_ = cvtpk(q2_, q3_);              \
    unsigned int wd0_ = cvtpk(q4_, q5_), wd1_ = cvtpk(q6_, q7_);              \
    ls_ += ((q0_ + q1_) + (q2_ + q3_)) + ((q4_ + q5_) + (q6_ + q7_));         \
    PSWAP(wa0_, wb0_);                                                        \
    PSWAP(wa1_, wb1_);                                                        \
    PSWAP(wc0_, wd0_);                                                        \
    PSWAP(wc1_, wd1_);                                                        \
    ls_ += __shfl_xor(ls_, 32);                                               \
    l = l * al_ + ls_;                                                        \
    _Pragma("unroll")                                                         \
    for (int r_ = 0; r_ < 16; ++r_) { o0[r_] *= al_; o1[r_] *= al_; }         \
    uint4 u0_ = {wa0_, wa1_, wb0_, wb1_};                                     \
    uint4 u1_ = {wc0_, wc1_, wd0_, wd1_};                                     \
    bf8 pf0_ = *reinterpret_cast<bf8*>(&u0_);                                 \
    bf8 pf1_ = *reinterpret_cast<bf8*>(&u1_);                                 \
    __builtin_amdgcn_s_setprio(1);                                            \
    o0 = mfma32(vf[0], pf0_, o0);                                             \
    o0 = mfma32(vf[1], pf1_, o0);                                             \
    o1 = mfma32(vf[2], pf0_, o1);                                             \
    o1 = mfma32(vf[3], pf1_, o1);                                             \
    __builtin_amdgcn_s_setprio(0);                                            \
  } while (0)

// ---- causal flash attention: paired q-tiles + split-K x4 + XCD chunking --
// Block = 4 waves, q-tiles {b, 127-b} -> uniform 129 tiles/block, 768
// blocks = exactly 3/CU. XCD chunk: W=(L&7)*96+(L>>3) -> 1.5 heads/XCD
// (K+V L2-resident, proven R6: FETCH 10.8MB). K and V register-double-
// buffered; straight-line code so the prefetch survives regalloc.
// Cross-half reduces via __shfl_xor(.,32) (PSWAP self-swap is UNSAFE:
// compiler may coalesce the two identical-valued operands into one reg).
__global__ __launch_bounds__(256, 3) void k_attn(const unsigned short* __restrict__ Qb,
                                                 const unsigned short* __restrict__ Kb,
                                                 const unsigned short* __restrict__ Vt,
                                                 unsigned short* __restrict__ ctx) {
  const int tid = threadIdx.x;
  const int lane = tid & 63;
  const int w = tid >> 6;  // split-K wave index, 0..3
  const int ql = lane & 31, hi = lane >> 5;

  const int L = (int)blockIdx.x;          // 0..767
  const int W = (L & 7) * 96 + (L >> 3);  // XCD-chunked work id
  const int h = W >> 6;
  const int b = W & 63;
  const size_t hd = (size_t)h * HD;

  __shared__ float sO[4][64][32];
  __shared__ float sM[4][32];
  __shared__ float sL[4][32];

  const unsigned short* Kbase = Kb + (size_t)ql * DM + hd + hi * 8;
  const unsigned short* Vbase = Vt + (hd + ql) * SEQ + hi * 8;

  for (int ph = 0; ph < 2; ++ph) {
    const int qt = ph ? (127 - b) : b;
    const int qg = qt * 32 + ql;
    // Q as B-fragments: col=q=lane&31, k(d)=8*hi+j
    bf8 qf[4];
    {
      const unsigned short* qp = Qb + (size_t)qg * DM + hd + hi * 8;
      qf[0] = *reinterpret_cast<const bf8*>(qp);
      qf[1] = *reinterpret_cast<const bf8*>(qp + 16);
      qf[2] = *reinterpret_cast<const bf8*>(qp + 32);
      qf[3] = *reinterpret_cast<const bf8*>(qp + 48);
    }
    f32x16 o0 = {}, o1 = {};
    float m = -1e30f, l = 0.f;

    const int nt = (qt >= w) ? ((qt - w) >> 2) + 1 : 0;
    bf8 kA[4], kB[4], vA[4], vB[4];
    if (nt > 0) LOADK(kA, w);
    int i = 0;
    for (; i + 2 <= nt; i += 2) {
      const int tA_ = w + 4 * i, tB_ = tA_ + 4;
      LOADV(vA, tA_);
      LOADK(kB, tB_);
      STEP(kA, vA, tA_);
      LOADV(vB, tB_);
      if (i + 2 < nt) LOADK(kA, tB_ + 4);
      STEP(kB, vB, tB_);
    }
    if (i < nt) {
      const int tA_ = w + 4 * i;
      LOADV(vA, tA_);
      STEP(kA, vA, tA_);
    }

    // ---- 4-way split-K merge via LDS ----
#pragma unroll
    for (int r = 0; r < 16; ++r) {
      int dr = (r & 3) + 8 * (r >> 2) + 4 * hi;
      sO[w][dr][ql] = o0[r];
      sO[w][32 + dr][ql] = o1[r];
    }
    if (hi == 0) { sM[w][ql] = m; sL[w][ql] = l; }
    __syncthreads();
    {
      const int q = tid & 31;
      const int dblk = tid >> 5;  // 0..7, 8 d-values each
      float m0 = sM[0][q], m1 = sM[1][q], m2 = sM[2][q], m3 = sM[3][q];
      float mn = fmaxf(fmaxf(m0, m1), fmaxf(m2, m3));
      float a0 = __builtin_amdgcn_exp2f(m0 - mn);
      float a1 = __builtin_amdgcn_exp2f(m1 - mn);
      float a2 = __builtin_amdgcn_exp2f(m2 - mn);
      float a3 = __builtin_amdgcn_exp2f(m3 - mn);
      float inv = 1.f / (a0 * sL[0][q] + a1 * sL[1][q] + a2 * sL[2][q] + a3 * sL[3][q]);
      a0 *= inv; a1 *= inv; a2 *= inv; a3 *= inv;
      unsigned short* cp = ctx + (size_t)(qt * 32 + q) * DM + hd + dblk * 8;
#pragma unroll
      for (int j = 0; j < 8; j += 2) {
        int d = dblk * 8 + j;
        float v0 = sO[0][d][q] * a0 + sO[1][d][q] * a1 + sO[2][d][q] * a2 + sO[3][d][q] * a3;
        float v1 = sO[0][d + 1][q] * a0 + sO[1][d + 1][q] * a1 + sO[2][d + 1][q] * a2 + sO[3][d + 1][q] * a3;
        *reinterpret_cast<unsigned int*>(cp + j) = cvtpk(v0, v1);
      }
    }
    __syncthreads();
  }
}

extern "C" void kernel_launch(void* const* d_in, const int* in_sizes, int n_in,
                              void* d_out, int out_size, void* d_ws, size_t ws_size,
                              hipStream_t stream) {
  const float* x  = (const float*)d_in[0];
  const float* Wq = (const float*)d_in[1];
  const float* Wk = (const float*)d_in[2];
  const float* Wv = (const float*)d_in[3];
  const float* Wo = (const float*)d_in[4];
  const float* bo = (const float*)d_in[5];

  unsigned short* xb = (unsigned short*)d_ws;
  unsigned short* wt = xb + (size_t)SEQ * DM;
  unsigned short* Qb = wt + (size_t)4 * DM * DM;
  unsigned short* Kb = Qb + (size_t)SEQ * DM;
  unsigned short* Vt = Kb + (size_t)SEQ * DM;
  unsigned short* cx = Vt + (size_t)SEQ * DM;

  const float qscale = 1.4426950408889634f / 8.0f;  // log2(e)/sqrt(HD)

  k_cvt<<<(SEQ * DM) / 1024, 256, 0, stream>>>(x, xb);
  k_tw<<<dim3(24, 24, 4), 256, 0, stream>>>(Wq, Wk, Wv, Wo, wt);
  dim3 gg(SEQ / 128, DM / 64);
  k_gemm<0><<<gg, 256, 0, stream>>>(xb, wt, Qb, nullptr, qscale);
  k_gemm<0><<<gg, 256, 0, stream>>>(xb, wt + (size_t)DM * DM, Kb, nullptr, 1.0f);
  k_gemm<1><<<gg, 256, 0, stream>>>(xb, wt + (size_t)2 * DM * DM, Vt, nullptr, 1.0f);
  k_attn<<<dim3(768), 256, 0, stream>>>(Qb, Kb, Vt, cx);
  k_gemm<2><<<gg, 256, 0, stream>>>(cx, wt + (size_t)3 * DM * DM, d_out, bo, 1.0f);
}